// Round 1
// baseline (841.644 us; speedup 1.0000x reference)
//
#include <hip/hip_runtime.h>
#include <hip/hip_bf16.h>

#define N_NODES 50000
#define N_EDGES 800000

// ---------------------------------------------------------------------------
// row_ptr[i] = lower_bound(src, i); src is sorted. row_ptr[N] = E.
// ---------------------------------------------------------------------------
__global__ __launch_bounds__(256) void rowptr_kernel(const int* __restrict__ src,
                                                     int* __restrict__ row_ptr,
                                                     int n, int e) {
    int i = blockIdx.x * 256 + threadIdx.x;
    if (i > n) return;
    int lo = 0, hi = e;
    while (lo < hi) {
        int mid = (lo + hi) >> 1;
        if (src[mid] < i) lo = mid + 1; else hi = mid;
    }
    row_ptr[i] = lo;
}

// ---------------------------------------------------------------------------
// h[i,f] = leaky_relu(sum_k in[i,k]*w[f,k] + b[f], 0.2);  F_out = 64 fixed.
// 16 rows per block, 256 threads: thread t -> (f = t&63, row group rg = t>>6)
// each thread computes 4 rows for its f. x tile staged in LDS; weight row
// streamed from global (64KB total, L1/L2 resident).
// ---------------------------------------------------------------------------
template <int K>
__global__ __launch_bounds__(256) void lin_kernel(const float* __restrict__ in,
                                                  const float* __restrict__ w,
                                                  const float* __restrict__ b,
                                                  float* __restrict__ h) {
    __shared__ float xs[16 * K];
    const int t = threadIdx.x;
    const long i0 = (long)blockIdx.x * 16;
    const float4* inv = (const float4*)(in + i0 * K);
    float4* xsv = (float4*)xs;
    const int nv = 16 * K / 4;
    for (int j = t; j < nv; j += 256) xsv[j] = inv[j];
    __syncthreads();

    const int f = t & 63;
    const int rg = t >> 6;  // 0..3 -> rows rg*4 .. rg*4+3
    float acc0 = 0.f, acc1 = 0.f, acc2 = 0.f, acc3 = 0.f;
    const float4* wv = (const float4*)(w + f * K);
    const float4* xrow = xsv + rg * 4 * (K / 4);
    #pragma unroll 4
    for (int k4 = 0; k4 < K / 4; ++k4) {
        float4 wk = wv[k4];
        float4 x0 = xrow[0 * (K / 4) + k4];
        float4 x1 = xrow[1 * (K / 4) + k4];
        float4 x2 = xrow[2 * (K / 4) + k4];
        float4 x3 = xrow[3 * (K / 4) + k4];
        acc0 += wk.x * x0.x + wk.y * x0.y + wk.z * x0.z + wk.w * x0.w;
        acc1 += wk.x * x1.x + wk.y * x1.y + wk.z * x1.z + wk.w * x1.w;
        acc2 += wk.x * x2.x + wk.y * x2.y + wk.z * x2.z + wk.w * x2.w;
        acc3 += wk.x * x3.x + wk.y * x3.y + wk.z * x3.z + wk.w * x3.w;
    }
    const float bias = b[f];
    float v0 = acc0 + bias, v1 = acc1 + bias, v2 = acc2 + bias, v3 = acc3 + bias;
    v0 = v0 > 0.f ? v0 : 0.2f * v0;
    v1 = v1 > 0.f ? v1 : 0.2f * v1;
    v2 = v2 > 0.f ? v2 : 0.2f * v2;
    v3 = v3 > 0.f ? v3 : 0.2f * v3;
    const long rb = (i0 + rg * 4) * 64 + f;
    h[rb + 0 * 64] = v0;
    h[rb + 1 * 64] = v1;
    h[rb + 2 * 64] = v2;
    h[rb + 3 * 64] = v3;
}

// ---------------------------------------------------------------------------
// s[i,h] = sum_f h[i,f] * (aw[h,f] + aw[h,64+f])
// (Wi nonzero for heads 0,1 acting on src; Wj nonzero for heads 2,3 acting on
//  dst; both equal aw[:, :64]+aw[:, 64:] — so one score per (node, head).)
// ---------------------------------------------------------------------------
__global__ __launch_bounds__(256) void score_kernel(const float* __restrict__ h,
                                                    const float* __restrict__ aw,
                                                    float* __restrict__ s, int n) {
    int idx = blockIdx.x * 256 + threadIdx.x;
    if (idx >= n * 4) return;
    int i = idx >> 2, hh = idx & 3;
    const float* hr = h + (long)i * 64;
    const float* a1 = aw + hh * 128;
    const float* a2 = a1 + 64;
    float acc = 0.f;
    #pragma unroll 8
    for (int f = 0; f < 64; ++f) acc += hr[f] * (a1[f] + a2[f]);
    s[idx] = acc;
}

// ---------------------------------------------------------------------------
// Per-node segment softmax + weighted aggregation.
// e[edge,h] = (h<2 ? s[i,h] : s[dst,h]) + ab[h]  (edges of node i: src==i)
// alpha = softmax over node i's edges (per head)
// out[i, f*4+h] = relu( sum_e alpha[e,h] * hfeat[dst_e, f] )   (non-final)
// out[i, f]     = relu( mean_h ... )                           (final)
// One block of 256 threads per node; thread t -> (f = t>>2, h = t&3).
// ---------------------------------------------------------------------------
__global__ __launch_bounds__(256) void agg_kernel(const float* __restrict__ hfeat,
                                                  const float* __restrict__ s,
                                                  const int* __restrict__ dst,
                                                  const int* __restrict__ row_ptr,
                                                  const float* __restrict__ ab,
                                                  float* __restrict__ out,
                                                  int final_layer) {
    const int i = blockIdx.x;
    const int t = threadIdx.x;
    const int r0 = row_ptr[i];
    const int r1 = row_ptr[i + 1];
    const int deg = r1 - r0;

    if (deg == 0) {
        // empty segment: segment_sum -> 0, relu(0) = 0.  Must write (poisoned buf).
        if (!final_layer) out[(long)i * 256 + t] = 0.f;
        else if (t < 64) out[(long)i * 64 + t] = 0.f;
        return;
    }

    __shared__ float m_s[4], sum_s[4];
    __shared__ float alpha_s[256];
    __shared__ int dst_s[64];

    const int hh = t & 3;
    const float abv = ab[hh];
    const float siv = s[i * 4 + hh] + abv;  // score term when head < 2 (constant per segment)

    // ---- Phase A: per-head max and sum of exp (wave 0 only) ----
    if (t < 64) {
        const int lane_e = t >> 2;  // 0..15, edge stride lane within head group
        float vmax = -INFINITY;
        for (int e = r0 + lane_e; e < r1; e += 16) {
            float v = (hh < 2) ? siv : (s[dst[e] * 4 + hh] + abv);
            vmax = fmaxf(vmax, v);
        }
        #pragma unroll
        for (int off = 4; off < 64; off <<= 1) vmax = fmaxf(vmax, __shfl_xor(vmax, off));
        float vsum = 0.f;
        for (int e = r0 + lane_e; e < r1; e += 16) {
            float v = (hh < 2) ? siv : (s[dst[e] * 4 + hh] + abv);
            vsum += __expf(v - vmax);
        }
        #pragma unroll
        for (int off = 4; off < 64; off <<= 1) vsum += __shfl_xor(vsum, off);
        if (t < 4) { m_s[t] = vmax; sum_s[t] = vsum; }
    }
    __syncthreads();

    const int f = t >> 2;
    const float m = m_s[hh];
    const float sinv = 1.f / sum_s[hh];
    float acc = 0.f;

    // ---- Phase B: chunked alpha + gather-accumulate ----
    for (int c0 = r0; c0 < r1; c0 += 64) {
        const int cn = min(64, r1 - c0);
        __syncthreads();  // protect alpha_s/dst_s reuse across chunks
        if (t < cn * 4) {
            const int e = c0 + (t >> 2);
            const int d = dst[e];
            if (hh == 0) dst_s[t >> 2] = d;
            float v = (hh < 2) ? siv : (s[d * 4 + hh] + abv);
            alpha_s[t] = __expf(v - m) * sinv;
        }
        __syncthreads();
        for (int j = 0; j < cn; ++j) {
            acc += alpha_s[j * 4 + hh] * hfeat[(long)dst_s[j] * 64 + f];
        }
    }

    if (!final_layer) {
        out[(long)i * 256 + t] = fmaxf(acc, 0.f);  // layout [i, f*H + h], t == f*4+h
    } else {
        float v = acc + __shfl_xor(acc, 1);
        v += __shfl_xor(v, 2);
        if (hh == 0) out[(long)i * 64 + f] = fmaxf(v * 0.25f, 0.f);
    }
}

// ---------------------------------------------------------------------------
extern "C" void kernel_launch(void* const* d_in, const int* in_sizes, int n_in,
                              void* d_out, int out_size, void* d_ws, size_t ws_size,
                              hipStream_t stream) {
    const float* x = (const float*)d_in[0];
    const float* lw[3] = {(const float*)d_in[1], (const float*)d_in[5], (const float*)d_in[9]};
    const float* lb[3] = {(const float*)d_in[2], (const float*)d_in[6], (const float*)d_in[10]};
    const float* aw[3] = {(const float*)d_in[3], (const float*)d_in[7], (const float*)d_in[11]};
    const float* ab[3] = {(const float*)d_in[4], (const float*)d_in[8], (const float*)d_in[12]};
    const int* src = (const int*)d_in[13];
    const int* dst = (const int*)d_in[14];
    float* out = (float*)d_out;

    const int N = N_NODES, E = N_EDGES;

    // workspace layout (floats): bufA[N*256] | h[N*64] | s[N*4] | row_ptr[N+1]
    float* bufA = (float*)d_ws;
    float* hbuf = bufA + (size_t)N * 256;
    float* sbuf = hbuf + (size_t)N * 64;
    int* row_ptr = (int*)(sbuf + (size_t)N * 4);

    rowptr_kernel<<<(N + 1 + 255) / 256, 256, 0, stream>>>(src, row_ptr, N, E);

    const int score_grid = (N * 4 + 255) / 256;

    // ---- layer 0 (K=128) ----
    lin_kernel<128><<<N / 16, 256, 0, stream>>>(x, lw[0], lb[0], hbuf);
    score_kernel<<<score_grid, 256, 0, stream>>>(hbuf, aw[0], sbuf, N);
    agg_kernel<<<N, 256, 0, stream>>>(hbuf, sbuf, dst, row_ptr, ab[0], bufA, 0);

    // ---- layer 1 (K=256) ----
    lin_kernel<256><<<N / 16, 256, 0, stream>>>(bufA, lw[1], lb[1], hbuf);
    score_kernel<<<score_grid, 256, 0, stream>>>(hbuf, aw[1], sbuf, N);
    agg_kernel<<<N, 256, 0, stream>>>(hbuf, sbuf, dst, row_ptr, ab[1], bufA, 0);

    // ---- layer 2 (K=256, final) ----
    lin_kernel<256><<<N / 16, 256, 0, stream>>>(bufA, lw[2], lb[2], hbuf);
    score_kernel<<<score_grid, 256, 0, stream>>>(hbuf, aw[2], sbuf, N);
    agg_kernel<<<N, 256, 0, stream>>>(hbuf, sbuf, dst, row_ptr, ab[2], out, 1);
}

// Round 2
// 362.790 us; speedup vs baseline: 2.3199x; 2.3199x over previous
//
#include <hip/hip_runtime.h>
#include <hip/hip_bf16.h>

#define N_NODES 50000
#define N_EDGES 800000

// ---------------------------------------------------------------------------
// row_ptr[i] = lower_bound(src, i); src is sorted. row_ptr[N] = E.
// ---------------------------------------------------------------------------
__global__ __launch_bounds__(256) void rowptr_kernel(const int* __restrict__ src,
                                                     int* __restrict__ row_ptr,
                                                     int n, int e) {
    int i = blockIdx.x * 256 + threadIdx.x;
    if (i > n) return;
    int lo = 0, hi = e;
    while (lo < hi) {
        int mid = (lo + hi) >> 1;
        if (src[mid] < i) lo = mid + 1; else hi = mid;
    }
    row_ptr[i] = lo;
}

// ---------------------------------------------------------------------------
// Fold duplicated head-0/1 input columns of lin1_w / lin2_w (64 x 256) into
// planar K=192 weights matching agg's output layout [i, c*64 + f]:
//   c=0 (mean channel, feeds heads 0 AND 1): w'[o, f]       = lw[o,4f] + lw[o,4f+1]
//   c=1 (alpha2 channel):                    w'[o, 64+f]    = lw[o,4f+2]
//   c=2 (alpha3 channel):                    w'[o, 128+f]   = lw[o,4f+3]
// ---------------------------------------------------------------------------
__global__ __launch_bounds__(256) void wprep_kernel(const float* __restrict__ lw1,
                                                    const float* __restrict__ lw2,
                                                    float* __restrict__ w1p,
                                                    float* __restrict__ w2p) {
    int idx = blockIdx.x * 256 + threadIdx.x;
    if (idx >= 64 * 192) return;
    int o = idx / 192, r = idx % 192;
    int c = r >> 6, f = r & 63;
    const float* lw = (blockIdx.y == 0) ? lw1 : lw2;
    float v;
    if (c == 0)      v = lw[o * 256 + f * 4 + 0] + lw[o * 256 + f * 4 + 1];
    else if (c == 1) v = lw[o * 256 + f * 4 + 2];
    else             v = lw[o * 256 + f * 4 + 3];
    (blockIdx.y == 0 ? w1p : w2p)[idx] = v;
}

// ---------------------------------------------------------------------------
// h[i,o] = leaky_relu(sum_k in[i,k]*w[o,k] + b[o], 0.2), o in [0,64).
// 64 rows x 64 cols per block, 256 threads, 4x4 register tile per thread,
// BK=16 LDS staging. Fused score epilogue:
//   s[i] = ( h_i . (aw[2,:64]+aw[2,64:]),  h_i . (aw[3,:64]+aw[3,64:]) )
// ---------------------------------------------------------------------------
template <int K>
__global__ __launch_bounds__(256) void lin_kernel(const float* __restrict__ in,
                                                  const float* __restrict__ w,
                                                  const float* __restrict__ b,
                                                  const float* __restrict__ aw,
                                                  float* __restrict__ h,
                                                  float2* __restrict__ s, int n) {
    __shared__ float xs[16][64];   // xs[kk][row]
    __shared__ float ws[16][64];   // ws[kk][col(o)]
    const int t = threadIdx.x;
    const int i0 = blockIdx.x * 64;
    const int row = t & 63, kq = t >> 6;        // staging role
    const int tx = t & 15, ty = (t & 63) >> 4;  // compute role (tile within wave-uniform map)
    const int txg = t & 15, tyg = t >> 4;       // full-block 16x16 map: rows tyg*4.., cols txg*4..

    float acc[4][4] = {};

    for (int k0 = 0; k0 < K; k0 += 16) {
        float4 xv = make_float4(0.f, 0.f, 0.f, 0.f);
        if (i0 + row < n) xv = *(const float4*)(in + (long)(i0 + row) * K + k0 + kq * 4);
        float4 wv = *(const float4*)(w + row * K + k0 + kq * 4);
        __syncthreads();
        xs[kq * 4 + 0][row] = xv.x; xs[kq * 4 + 1][row] = xv.y;
        xs[kq * 4 + 2][row] = xv.z; xs[kq * 4 + 3][row] = xv.w;
        ws[kq * 4 + 0][row] = wv.x; ws[kq * 4 + 1][row] = wv.y;
        ws[kq * 4 + 2][row] = wv.z; ws[kq * 4 + 3][row] = wv.w;
        __syncthreads();
        #pragma unroll
        for (int kk = 0; kk < 16; ++kk) {
            float4 a = *(const float4*)&xs[kk][tyg * 4];
            float4 bb = *(const float4*)&ws[kk][txg * 4];
            acc[0][0] += a.x * bb.x; acc[0][1] += a.x * bb.y; acc[0][2] += a.x * bb.z; acc[0][3] += a.x * bb.w;
            acc[1][0] += a.y * bb.x; acc[1][1] += a.y * bb.y; acc[1][2] += a.y * bb.z; acc[1][3] += a.y * bb.w;
            acc[2][0] += a.z * bb.x; acc[2][1] += a.z * bb.y; acc[2][2] += a.z * bb.z; acc[2][3] += a.z * bb.w;
            acc[3][0] += a.w * bb.x; acc[3][1] += a.w * bb.y; acc[3][2] += a.w * bb.z; acc[3][3] += a.w * bb.w;
        }
    }

    // epilogue: bias + leaky relu
    const float4 bias = *(const float4*)(b + txg * 4);
    float v[4][4];
    #pragma unroll
    for (int r = 0; r < 4; ++r) {
        v[r][0] = acc[r][0] + bias.x; v[r][1] = acc[r][1] + bias.y;
        v[r][2] = acc[r][2] + bias.z; v[r][3] = acc[r][3] + bias.w;
        #pragma unroll
        for (int c = 0; c < 4; ++c) v[r][c] = v[r][c] > 0.f ? v[r][c] : 0.2f * v[r][c];
    }
    #pragma unroll
    for (int r = 0; r < 4; ++r) {
        int i = i0 + tyg * 4 + r;
        if (i < n) *(float4*)(h + (long)i * 64 + txg * 4) = make_float4(v[r][0], v[r][1], v[r][2], v[r][3]);
    }

    // fused score: per-row dot with combined attention vectors a2, a3
    float a2c[4], a3c[4];
    #pragma unroll
    for (int c = 0; c < 4; ++c) {
        int col = txg * 4 + c;
        a2c[c] = aw[2 * 128 + col] + aw[2 * 128 + 64 + col];
        a3c[c] = aw[3 * 128 + col] + aw[3 * 128 + 64 + col];
    }
    #pragma unroll
    for (int r = 0; r < 4; ++r) {
        float q2 = v[r][0] * a2c[0] + v[r][1] * a2c[1] + v[r][2] * a2c[2] + v[r][3] * a2c[3];
        float q3 = v[r][0] * a3c[0] + v[r][1] * a3c[1] + v[r][2] * a3c[2] + v[r][3] * a3c[3];
        #pragma unroll
        for (int o = 1; o < 16; o <<= 1) { q2 += __shfl_xor(q2, o); q3 += __shfl_xor(q3, o); }
        int i = i0 + tyg * 4 + r;
        if ((t & 15) == 0 && i < n) s[i] = make_float2(q2, q3);
    }
    (void)row; (void)kq; (void)tx; (void)ty;
}

// ---------------------------------------------------------------------------
// Wave-per-node aggregation (4 nodes per 256-thread block, no __syncthreads).
// lane l: channel c = l>>4 in {0:mean, 1:mean(dup), 2:alpha2, 3:alpha3},
//         feature chunk f4 = l&15 -> floats f4*4 .. f4*4+3.
// Heads 0,1: alpha uniform = 1/deg (e constant per segment) -> mean channel.
// Heads 2,3: softmax over s[dst] (ab cancels).
// Non-final out layout: [i, c'*64 + f], c' in {0:mean,1:a2,2:a3} (192 cols).
// Final: out[i,f] = relu(0.5*mean + 0.25*(a2sum + a3sum)).
// ---------------------------------------------------------------------------
__global__ __launch_bounds__(256) void agg_kernel(const float* __restrict__ hfeat,
                                                  const float2* __restrict__ s,
                                                  const int* __restrict__ dst,
                                                  const int* __restrict__ row_ptr,
                                                  float* __restrict__ out,
                                                  int final_layer, int n) {
    const int t = threadIdx.x;
    const int l = t & 63;
    const int i = blockIdx.x * 4 + (t >> 6);
    if (i >= n) return;
    const int r0 = row_ptr[i], r1 = row_ptr[i + 1];
    const int deg = r1 - r0;
    const int c = l >> 4, f4 = l & 15;
    const float4 z4 = make_float4(0.f, 0.f, 0.f, 0.f);

    if (deg == 0) {
        if (!final_layer) {
            if (c == 0)      *(float4*)(out + (long)i * 192 + f4 * 4) = z4;
            else if (c == 2) *(float4*)(out + (long)i * 192 + 64 + f4 * 4) = z4;
            else if (c == 3) *(float4*)(out + (long)i * 192 + 128 + f4 * 4) = z4;
        } else if (c == 0) {
            *(float4*)(out + (long)i * 64 + f4 * 4) = z4;
        }
        return;
    }

    float4 acc = z4;
    float inv_deg = 1.f / (float)deg;

    if (deg <= 64) {
        // ---- phase A: lane-parallel softmax over edges (heads 2,3) ----
        int dl = 0;
        float g2 = -INFINITY, g3 = -INFINITY;
        if (l < deg) {
            dl = dst[r0 + l];
            float2 sv = s[dl];
            g2 = sv.x; g3 = sv.y;
        }
        float m2 = g2, m3 = g3;
        #pragma unroll
        for (int o = 1; o < 64; o <<= 1) {
            m2 = fmaxf(m2, __shfl_xor(m2, o));
            m3 = fmaxf(m3, __shfl_xor(m3, o));
        }
        float p2 = (l < deg) ? __expf(g2 - m2) : 0.f;
        float p3 = (l < deg) ? __expf(g3 - m3) : 0.f;
        float S2 = p2, S3 = p3;
        #pragma unroll
        for (int o = 1; o < 64; o <<= 1) { S2 += __shfl_xor(S2, o); S3 += __shfl_xor(S3, o); }
        float a2 = p2 / S2, a3 = p3 / S3;

        // ---- phase B: broadcast dst/alpha via shuffle, coalesced row gather ----
        for (int j = 0; j < deg; ++j) {
            int d = __shfl(dl, j);
            float w2 = __shfl(a2, j);
            float w3 = __shfl(a3, j);
            float wgt = (c < 2) ? 1.f : (c == 2 ? w2 : w3);
            const float4 hv = *(const float4*)(hfeat + (long)d * 64 + f4 * 4);
            acc.x += wgt * hv.x; acc.y += wgt * hv.y;
            acc.z += wgt * hv.z; acc.w += wgt * hv.w;
        }
    } else {
        // ---- generic fallback (deg > 64), rare ----
        float m2 = -INFINITY, m3 = -INFINITY;
        for (int e = r0 + l; e < r1; e += 64) {
            float2 sv = s[dst[e]];
            m2 = fmaxf(m2, sv.x); m3 = fmaxf(m3, sv.y);
        }
        #pragma unroll
        for (int o = 1; o < 64; o <<= 1) {
            m2 = fmaxf(m2, __shfl_xor(m2, o));
            m3 = fmaxf(m3, __shfl_xor(m3, o));
        }
        float S2 = 0.f, S3 = 0.f;
        for (int e = r0 + l; e < r1; e += 64) {
            float2 sv = s[dst[e]];
            S2 += __expf(sv.x - m2); S3 += __expf(sv.y - m3);
        }
        #pragma unroll
        for (int o = 1; o < 64; o <<= 1) { S2 += __shfl_xor(S2, o); S3 += __shfl_xor(S3, o); }
        float i2 = 1.f / S2, i3 = 1.f / S3;
        for (int e = r0; e < r1; ++e) {
            int d = dst[e];
            float wgt;
            if (c < 2) wgt = 1.f;
            else {
                float2 sv = s[d];
                wgt = (c == 2) ? __expf(sv.x - m2) * i2 : __expf(sv.y - m3) * i3;
            }
            const float4 hv = *(const float4*)(hfeat + (long)d * 64 + f4 * 4);
            acc.x += wgt * hv.x; acc.y += wgt * hv.y;
            acc.z += wgt * hv.z; acc.w += wgt * hv.w;
        }
    }

    if (!final_layer) {
        if (c == 0) {
            float4 r4 = make_float4(fmaxf(acc.x * inv_deg, 0.f), fmaxf(acc.y * inv_deg, 0.f),
                                    fmaxf(acc.z * inv_deg, 0.f), fmaxf(acc.w * inv_deg, 0.f));
            *(float4*)(out + (long)i * 192 + f4 * 4) = r4;
        } else if (c == 2) {
            float4 r4 = make_float4(fmaxf(acc.x, 0.f), fmaxf(acc.y, 0.f),
                                    fmaxf(acc.z, 0.f), fmaxf(acc.w, 0.f));
            *(float4*)(out + (long)i * 192 + 64 + f4 * 4) = r4;
        } else if (c == 3) {
            float4 r4 = make_float4(fmaxf(acc.x, 0.f), fmaxf(acc.y, 0.f),
                                    fmaxf(acc.z, 0.f), fmaxf(acc.w, 0.f));
            *(float4*)(out + (long)i * 192 + 128 + f4 * 4) = r4;
        }
    } else {
        // out[i,f] = relu( (2*mean + a2sum + a3sum) / 4 )
        float4 r4;
        r4.x = fmaxf(0.f, 0.5f * inv_deg * acc.x + 0.25f * (__shfl(acc.x, 32 + f4) + __shfl(acc.x, 48 + f4)));
        r4.y = fmaxf(0.f, 0.5f * inv_deg * acc.y + 0.25f * (__shfl(acc.y, 32 + f4) + __shfl(acc.y, 48 + f4)));
        r4.z = fmaxf(0.f, 0.5f * inv_deg * acc.z + 0.25f * (__shfl(acc.z, 32 + f4) + __shfl(acc.z, 48 + f4)));
        r4.w = fmaxf(0.f, 0.5f * inv_deg * acc.w + 0.25f * (__shfl(acc.w, 32 + f4) + __shfl(acc.w, 48 + f4)));
        if (c == 0) *(float4*)(out + (long)i * 64 + f4 * 4) = r4;
    }
}

// ---------------------------------------------------------------------------
extern "C" void kernel_launch(void* const* d_in, const int* in_sizes, int n_in,
                              void* d_out, int out_size, void* d_ws, size_t ws_size,
                              hipStream_t stream) {
    const float* x = (const float*)d_in[0];
    const float* lw[3] = {(const float*)d_in[1], (const float*)d_in[5], (const float*)d_in[9]};
    const float* lb[3] = {(const float*)d_in[2], (const float*)d_in[6], (const float*)d_in[10]};
    const float* aw[3] = {(const float*)d_in[3], (const float*)d_in[7], (const float*)d_in[11]};
    const int* src = (const int*)d_in[13];
    const int* dst = (const int*)d_in[14];
    float* out = (float*)d_out;

    const int N = N_NODES, E = N_EDGES;

    // ws layout (floats): bufA[N*192] | h[N*64] | s[N*2] | w1p[64*192] | w2p[64*192] | row_ptr[N+1]
    float* bufA = (float*)d_ws;
    float* hbuf = bufA + (size_t)N * 192;
    float2* sbuf = (float2*)(hbuf + (size_t)N * 64);
    float* w1p = (float*)(sbuf + N);
    float* w2p = w1p + 64 * 192;
    int* row_ptr = (int*)(w2p + 64 * 192);

    rowptr_kernel<<<(N + 1 + 255) / 256, 256, 0, stream>>>(src, row_ptr, N, E);
    wprep_kernel<<<dim3(48, 2), 256, 0, stream>>>(lw[1], lw[2], w1p, w2p);

    const int lin_grid = (N + 63) / 64;
    const int agg_grid = (N + 3) / 4;

    // ---- layer 0 ----
    lin_kernel<128><<<lin_grid, 256, 0, stream>>>(x, lw[0], lb[0], aw[0], hbuf, sbuf, N);
    agg_kernel<<<agg_grid, 256, 0, stream>>>(hbuf, sbuf, dst, row_ptr, bufA, 0, N);

    // ---- layer 1 ----
    lin_kernel<192><<<lin_grid, 256, 0, stream>>>(bufA, w1p, lb[1], aw[1], hbuf, sbuf, N);
    agg_kernel<<<agg_grid, 256, 0, stream>>>(hbuf, sbuf, dst, row_ptr, bufA, 0, N);

    // ---- layer 2 (final) ----
    lin_kernel<192><<<lin_grid, 256, 0, stream>>>(bufA, w2p, lb[2], aw[2], hbuf, sbuf, N);
    agg_kernel<<<agg_grid, 256, 0, stream>>>(hbuf, sbuf, dst, row_ptr, out, 1, N);
}

// Round 3
// 352.389 us; speedup vs baseline: 2.3884x; 1.0295x over previous
//
#include <hip/hip_runtime.h>
#include <hip/hip_bf16.h>

#define N_NODES 50000
#define N_EDGES 800000

static __device__ __forceinline__ float readlane_f(float v, int lane) {
    return __int_as_float(__builtin_amdgcn_readlane(__float_as_int(v), lane));
}

// ---------------------------------------------------------------------------
// row_ptr[i] = lower_bound(src, i); src is sorted. row_ptr[N] = E.
// ---------------------------------------------------------------------------
__global__ __launch_bounds__(256) void rowptr_kernel(const int* __restrict__ src,
                                                     int* __restrict__ row_ptr,
                                                     int n, int e) {
    int i = blockIdx.x * 256 + threadIdx.x;
    if (i > n) return;
    int lo = 0, hi = e;
    while (lo < hi) {
        int mid = (lo + hi) >> 1;
        if (src[mid] < i) lo = mid + 1; else hi = mid;
    }
    row_ptr[i] = lo;
}

// ---------------------------------------------------------------------------
// Fold duplicated head-0/1 input columns of lin1_w / lin2_w (64 x 256) into
// planar K=192 weights matching agg's output layout [i, c*64 + f]:
//   c=0 (mean channel, feeds heads 0 AND 1): w'[o, f]       = lw[o,4f] + lw[o,4f+1]
//   c=1 (alpha2 channel):                    w'[o, 64+f]    = lw[o,4f+2]
//   c=2 (alpha3 channel):                    w'[o, 128+f]   = lw[o,4f+3]
// ---------------------------------------------------------------------------
__global__ __launch_bounds__(256) void wprep_kernel(const float* __restrict__ lw1,
                                                    const float* __restrict__ lw2,
                                                    float* __restrict__ w1p,
                                                    float* __restrict__ w2p) {
    int idx = blockIdx.x * 256 + threadIdx.x;
    if (idx >= 64 * 192) return;
    int o = idx / 192, r = idx % 192;
    int c = r >> 6, f = r & 63;
    const float* lw = (blockIdx.y == 0) ? lw1 : lw2;
    float v;
    if (c == 0)      v = lw[o * 256 + f * 4 + 0] + lw[o * 256 + f * 4 + 1];
    else if (c == 1) v = lw[o * 256 + f * 4 + 2];
    else             v = lw[o * 256 + f * 4 + 3];
    (blockIdx.y == 0 ? w1p : w2p)[idx] = v;
}

// ---------------------------------------------------------------------------
// h[i,o] = leaky_relu(sum_k in[i,k]*w[o,k] + b[o], 0.2), o in [0,64).
// 64 rows x 64 cols per block, 256 threads, 4x4 register tile per thread,
// BK=16 LDS staging. Fused score epilogue:
//   s[i] = ( h_i . (aw[2,:64]+aw[2,64:]),  h_i . (aw[3,:64]+aw[3,64:]) )
// ---------------------------------------------------------------------------
template <int K>
__global__ __launch_bounds__(256) void lin_kernel(const float* __restrict__ in,
                                                  const float* __restrict__ w,
                                                  const float* __restrict__ b,
                                                  const float* __restrict__ aw,
                                                  float* __restrict__ h,
                                                  float2* __restrict__ s, int n) {
    __shared__ float xs[16][64];   // xs[kk][row]
    __shared__ float ws[16][64];   // ws[kk][col(o)]
    const int t = threadIdx.x;
    const int i0 = blockIdx.x * 64;
    const int row = t & 63, kq = t >> 6;        // staging role
    const int txg = t & 15, tyg = t >> 4;       // full-block 16x16 map: rows tyg*4.., cols txg*4..

    float acc[4][4] = {};

    for (int k0 = 0; k0 < K; k0 += 16) {
        float4 xv = make_float4(0.f, 0.f, 0.f, 0.f);
        if (i0 + row < n) xv = *(const float4*)(in + (long)(i0 + row) * K + k0 + kq * 4);
        float4 wv = *(const float4*)(w + row * K + k0 + kq * 4);
        __syncthreads();
        xs[kq * 4 + 0][row] = xv.x; xs[kq * 4 + 1][row] = xv.y;
        xs[kq * 4 + 2][row] = xv.z; xs[kq * 4 + 3][row] = xv.w;
        ws[kq * 4 + 0][row] = wv.x; ws[kq * 4 + 1][row] = wv.y;
        ws[kq * 4 + 2][row] = wv.z; ws[kq * 4 + 3][row] = wv.w;
        __syncthreads();
        #pragma unroll
        for (int kk = 0; kk < 16; ++kk) {
            float4 a = *(const float4*)&xs[kk][tyg * 4];
            float4 bb = *(const float4*)&ws[kk][txg * 4];
            acc[0][0] += a.x * bb.x; acc[0][1] += a.x * bb.y; acc[0][2] += a.x * bb.z; acc[0][3] += a.x * bb.w;
            acc[1][0] += a.y * bb.x; acc[1][1] += a.y * bb.y; acc[1][2] += a.y * bb.z; acc[1][3] += a.y * bb.w;
            acc[2][0] += a.z * bb.x; acc[2][1] += a.z * bb.y; acc[2][2] += a.z * bb.z; acc[2][3] += a.z * bb.w;
            acc[3][0] += a.w * bb.x; acc[3][1] += a.w * bb.y; acc[3][2] += a.w * bb.z; acc[3][3] += a.w * bb.w;
        }
    }

    // epilogue: bias + leaky relu
    const float4 bias = *(const float4*)(b + txg * 4);
    float v[4][4];
    #pragma unroll
    for (int r = 0; r < 4; ++r) {
        v[r][0] = acc[r][0] + bias.x; v[r][1] = acc[r][1] + bias.y;
        v[r][2] = acc[r][2] + bias.z; v[r][3] = acc[r][3] + bias.w;
        #pragma unroll
        for (int c = 0; c < 4; ++c) v[r][c] = v[r][c] > 0.f ? v[r][c] : 0.2f * v[r][c];
    }
    #pragma unroll
    for (int r = 0; r < 4; ++r) {
        int i = i0 + tyg * 4 + r;
        if (i < n) *(float4*)(h + (long)i * 64 + txg * 4) = make_float4(v[r][0], v[r][1], v[r][2], v[r][3]);
    }

    // fused score: per-row dot with combined attention vectors a2, a3
    float a2c[4], a3c[4];
    #pragma unroll
    for (int c = 0; c < 4; ++c) {
        int col = txg * 4 + c;
        a2c[c] = aw[2 * 128 + col] + aw[2 * 128 + 64 + col];
        a3c[c] = aw[3 * 128 + col] + aw[3 * 128 + 64 + col];
    }
    #pragma unroll
    for (int r = 0; r < 4; ++r) {
        float q2 = v[r][0] * a2c[0] + v[r][1] * a2c[1] + v[r][2] * a2c[2] + v[r][3] * a2c[3];
        float q3 = v[r][0] * a3c[0] + v[r][1] * a3c[1] + v[r][2] * a3c[2] + v[r][3] * a3c[3];
        #pragma unroll
        for (int o = 1; o < 16; o <<= 1) { q2 += __shfl_xor(q2, o); q3 += __shfl_xor(q3, o); }
        int i = i0 + tyg * 4 + r;
        if ((t & 15) == 0 && i < n) s[i] = make_float2(q2, q3);
    }
}

// ---------------------------------------------------------------------------
// Wave-per-node aggregation, lane = feature (64 lanes <-> 64 features).
// Each lane keeps 3 accumulators: mean (heads 0,1 have uniform alpha=1/deg),
// alpha2-weighted, alpha3-weighted. Per edge: ONE coalesced dword load
// (256 B row read exactly once per wave), 3 readlane broadcasts, 3 FMA.
// Non-final out layout: [i, c*64 + f], c in {0:mean,1:a2,2:a3} (192 cols).
// Final: out[i,f] = relu(0.5*inv_deg*mean + 0.25*(a2sum + a3sum)) — lane-local.
// ---------------------------------------------------------------------------
__global__ __launch_bounds__(256) void agg_kernel(const float* __restrict__ hfeat,
                                                  const float2* __restrict__ s,
                                                  const int* __restrict__ dst,
                                                  const int* __restrict__ row_ptr,
                                                  float* __restrict__ out,
                                                  int final_layer, int n) {
    const int t = threadIdx.x;
    const int l = t & 63;
    const int i = blockIdx.x * 4 + (t >> 6);
    if (i >= n) return;
    const int r0 = row_ptr[i], r1 = row_ptr[i + 1];
    const int deg = r1 - r0;

    if (deg == 0) {
        if (!final_layer) {
            out[(long)i * 192 + l] = 0.f;
            out[(long)i * 192 + 64 + l] = 0.f;
            out[(long)i * 192 + 128 + l] = 0.f;
        } else {
            out[(long)i * 64 + l] = 0.f;
        }
        return;
    }

    const float inv_deg = 1.f / (float)deg;
    float accm = 0.f, acc2 = 0.f, acc3 = 0.f;

    if (deg <= 64) {
        // ---- phase A: lane-parallel softmax over edges (heads 2,3) ----
        int dl = 0;
        float g2 = -INFINITY, g3 = -INFINITY;
        if (l < deg) {
            dl = dst[r0 + l];
            float2 sv = s[dl];
            g2 = sv.x; g3 = sv.y;
        }
        float m2 = g2, m3 = g3;
        #pragma unroll
        for (int o = 1; o < 64; o <<= 1) {
            m2 = fmaxf(m2, __shfl_xor(m2, o));
            m3 = fmaxf(m3, __shfl_xor(m3, o));
        }
        float p2 = (l < deg) ? __expf(g2 - m2) : 0.f;
        float p3 = (l < deg) ? __expf(g3 - m3) : 0.f;
        float S2 = p2, S3 = p3;
        #pragma unroll
        for (int o = 1; o < 64; o <<= 1) { S2 += __shfl_xor(S2, o); S3 += __shfl_xor(S3, o); }
        float a2 = p2 / S2, a3 = p3 / S3;

        // ---- phase B: readlane-broadcast + single coalesced row read ----
        for (int j = 0; j < deg; ++j) {
            int d = __builtin_amdgcn_readlane(dl, j);
            float w2 = readlane_f(a2, j);
            float w3 = readlane_f(a3, j);
            float hv = hfeat[(long)d * 64 + l];
            accm += hv;
            acc2 += w2 * hv;
            acc3 += w3 * hv;
        }
    } else {
        // ---- generic fallback (deg > 64), rare ----
        float m2 = -INFINITY, m3 = -INFINITY;
        for (int e = r0 + l; e < r1; e += 64) {
            float2 sv = s[dst[e]];
            m2 = fmaxf(m2, sv.x); m3 = fmaxf(m3, sv.y);
        }
        #pragma unroll
        for (int o = 1; o < 64; o <<= 1) {
            m2 = fmaxf(m2, __shfl_xor(m2, o));
            m3 = fmaxf(m3, __shfl_xor(m3, o));
        }
        float S2 = 0.f, S3 = 0.f;
        for (int e = r0 + l; e < r1; e += 64) {
            float2 sv = s[dst[e]];
            S2 += __expf(sv.x - m2); S3 += __expf(sv.y - m3);
        }
        #pragma unroll
        for (int o = 1; o < 64; o <<= 1) { S2 += __shfl_xor(S2, o); S3 += __shfl_xor(S3, o); }
        const float i2 = 1.f / S2, i3 = 1.f / S3;

        for (int c0 = r0; c0 < r1; c0 += 64) {
            const int cn = min(64, r1 - c0);
            int dl = 0;
            float w2l = 0.f, w3l = 0.f;
            if (l < cn) {
                dl = dst[c0 + l];
                float2 sv = s[dl];
                w2l = __expf(sv.x - m2) * i2;
                w3l = __expf(sv.y - m3) * i3;
            }
            for (int j = 0; j < cn; ++j) {
                int d = __builtin_amdgcn_readlane(dl, j);
                float w2 = readlane_f(w2l, j);
                float w3 = readlane_f(w3l, j);
                float hv = hfeat[(long)d * 64 + l];
                accm += hv;
                acc2 += w2 * hv;
                acc3 += w3 * hv;
            }
        }
    }

    if (!final_layer) {
        out[(long)i * 192 + l]       = fmaxf(accm * inv_deg, 0.f);
        out[(long)i * 192 + 64 + l]  = fmaxf(acc2, 0.f);
        out[(long)i * 192 + 128 + l] = fmaxf(acc3, 0.f);
    } else {
        out[(long)i * 64 + l] = fmaxf(0.5f * inv_deg * accm + 0.25f * (acc2 + acc3), 0.f);
    }
}

// ---------------------------------------------------------------------------
extern "C" void kernel_launch(void* const* d_in, const int* in_sizes, int n_in,
                              void* d_out, int out_size, void* d_ws, size_t ws_size,
                              hipStream_t stream) {
    const float* x = (const float*)d_in[0];
    const float* lw[3] = {(const float*)d_in[1], (const float*)d_in[5], (const float*)d_in[9]};
    const float* lb[3] = {(const float*)d_in[2], (const float*)d_in[6], (const float*)d_in[10]};
    const float* aw[3] = {(const float*)d_in[3], (const float*)d_in[7], (const float*)d_in[11]};
    const int* src = (const int*)d_in[13];
    const int* dst = (const int*)d_in[14];
    float* out = (float*)d_out;

    const int N = N_NODES, E = N_EDGES;

    // ws layout (floats): bufA[N*192] | h[N*64] | s[N*2] | w1p[64*192] | w2p[64*192] | row_ptr[N+1]
    float* bufA = (float*)d_ws;
    float* hbuf = bufA + (size_t)N * 192;
    float2* sbuf = (float2*)(hbuf + (size_t)N * 64);
    float* w1p = (float*)(sbuf + N);
    float* w2p = w1p + 64 * 192;
    int* row_ptr = (int*)(w2p + 64 * 192);

    rowptr_kernel<<<(N + 1 + 255) / 256, 256, 0, stream>>>(src, row_ptr, N, E);
    wprep_kernel<<<dim3(48, 2), 256, 0, stream>>>(lw[1], lw[2], w1p, w2p);

    const int lin_grid = (N + 63) / 64;
    const int agg_grid = (N + 3) / 4;

    // ---- layer 0 ----
    lin_kernel<128><<<lin_grid, 256, 0, stream>>>(x, lw[0], lb[0], aw[0], hbuf, sbuf, N);
    agg_kernel<<<agg_grid, 256, 0, stream>>>(hbuf, sbuf, dst, row_ptr, bufA, 0, N);

    // ---- layer 1 ----
    lin_kernel<192><<<lin_grid, 256, 0, stream>>>(bufA, w1p, lb[1], aw[1], hbuf, sbuf, N);
    agg_kernel<<<agg_grid, 256, 0, stream>>>(hbuf, sbuf, dst, row_ptr, bufA, 0, N);

    // ---- layer 2 (final) ----
    lin_kernel<192><<<lin_grid, 256, 0, stream>>>(bufA, w2p, lb[2], aw[2], hbuf, sbuf, N);
    agg_kernel<<<agg_grid, 256, 0, stream>>>(hbuf, sbuf, dst, row_ptr, out, 1, N);
}